// Round 10
// baseline (408.231 us; speedup 1.0000x reference)
//
#include <hip/hip_runtime.h>
#include <hip/hip_bf16.h>
#include <math.h>

// GRACE-style graph contrastive loss, MI355X (gfx950).
// R10: gram5_k — 512-thread blocks, 8 waves x (32x64) tiles per 128x128 supertile.
// Rationale: VGPR_Count=64 excluded AGPRs; real footprint was 64+64=128 regs ->
// 4 waves/SIMD cap, which explains gram3==gram4==56us. acc[2][4] (32 regs) ->
// ~90 total -> 5 waves/SIMD. Cross-wave sums via LDS atomicAdd (ds_add_f32,
// fire-and-forget) after 2-level shuffle pre-fold. LDS 33.8KB -> 4 blocks/CU.
// R7 lesson: launch_bounds floor kept loose (512,2) so allocator never spills.

#define NROWS 8192
#define MROWS 16384
#define NEDGE 262144

typedef __attribute__((ext_vector_type(8))) short bf16x8;
typedef __attribute__((ext_vector_type(4))) float f32x4;
typedef __attribute__((ext_vector_type(2))) float f32x2;
typedef long long i64;

__device__ __forceinline__ short f2bf(float f){
  union { float f; unsigned u; } cv; cv.f = f;
  unsigned u = cv.u;
  unsigned r = (u + 0x7fffu + ((u >> 16) & 1u)) >> 16;  // RNE; inputs finite
  return (short)r;
}
__device__ __forceinline__ f32x4 mfma16(bf16x8 a, bf16x8 b, f32x4 c){
  return __builtin_amdgcn_mfma_f32_16x16x32_bf16(a, b, c, 0, 0, 0);
}
__device__ __forceinline__ float fexp2(float x){
#if __has_builtin(__builtin_amdgcn_exp2f)
  return __builtin_amdgcn_exp2f(x);   // raw v_exp_f32; args bounded |x|<3
#else
  return exp2f(x);
#endif
}

// ---- fp8 e4m3fn pack (RNE) ----
__device__ unsigned char f2e4m3_sw(float f){
  float a = fabsf(f);
  unsigned s = (__float_as_uint(f)>>24)&0x80u;
  if (!(a>0.f)) return (unsigned char)s;
  if (a>448.f) a=448.f;
  int e; frexpf(a,&e);
  int eff=e-1;
  unsigned code;
  if (eff<-6){
    float q=rintf(a*512.f);
    code=(unsigned)q; if(code>7)code=7;
  } else {
    float q=rintf(a*exp2f((float)(3-eff)));
    unsigned mant=(unsigned)q;
    if(mant>=16){mant=8;eff++;}
    if(eff>8) return (unsigned char)(s|0x7e);
    code=((unsigned)(eff+7)<<3)|(mant-8);
  }
  return (unsigned char)(s|code);
}
__device__ __forceinline__ unsigned short pack2fp8(float a, float b){
#if __has_builtin(__builtin_amdgcn_cvt_pk_fp8_f32)
  int v = __builtin_amdgcn_cvt_pk_fp8_f32(a, b, 0, false);
  return (unsigned short)(v & 0xffff);
#else
  return (unsigned short)((unsigned)f2e4m3_sw(a) | ((unsigned)f2e4m3_sw(b)<<8));
#endif
}

// ---- fused setup: weight transpose+bf16 | degree histogram | feat fp32->bf16 ----
struct WtArgs {
  const float* src[6];
  short* dst[6];
  int K[6], N[6];
  int off[7];
  int nwt;
};
__global__ void setup_k(WtArgs a, const int* __restrict__ ei1, const int* __restrict__ ei2,
                        int* __restrict__ deg1, int* __restrict__ deg2,
                        const float* __restrict__ feat1, const float* __restrict__ feat2,
                        short* __restrict__ fb){
  int b = blockIdx.x;
  if (b < a.nwt){
    int i = b*256 + threadIdx.x;
    if (i >= a.off[6]) return;
    int s = 0;
    #pragma unroll
    for (int j=1;j<6;j++) if (i >= a.off[j]) s=j;
    int l = i - a.off[s];
    int K=a.K[s], N=a.N[s];
    int k=l/N, n=l-k*N;
    a.dst[s][(long)n*K+k] = f2bf(a.src[s][l]);
  } else if (b < a.nwt + 2*(NEDGE/256)){
    int hb = b - a.nwt;
    const int* ei = (hb < NEDGE/256) ? ei1 : ei2;
    int* deg = (hb < NEDGE/256) ? deg1 : deg2;
    int e = (hb % (NEDGE/256))*256 + threadIdx.x;
    atomicAdd(&deg[ei[e]], 1);
  } else {
    int idx = (b - a.nwt - 2*(NEDGE/256))*256 + threadIdx.x;   // float4 idx
    int row = idx >> 7, c4 = idx & 127;
    const float* src = (row < NROWS) ? (feat1 + (long)row*512 + c4*4)
                                     : (feat2 + (long)(row-NROWS)*512 + c4*4);
    float4 f = *(const float4*)src;
    uint2 o;
    o.x = (unsigned)(unsigned short)f2bf(f.x) | ((unsigned)(unsigned short)f2bf(f.y)<<16);
    o.y = (unsigned)(unsigned short)f2bf(f.z) | ((unsigned)(unsigned short)f2bf(f.w)<<16);
    *(uint2*)(fb + (long)row*512 + c4*4) = o;
  }
}

// ---- generic tall-skinny MFMA GEMM: Out[M,NN] = act(A[M,KK] @ Bt[NN,KK]^T + bias) ----
template<int NN, int KK, int ACT, bool BIAS, bool OUTF32>
__global__ __launch_bounds__(256) void gemm_k(const void* __restrict__ A0,
                                              const short* __restrict__ Bt, const float* __restrict__ bias,
                                              void* __restrict__ Out){
  constexpr int WM = (NN >= 64) ? 64 : 16;
  constexpr int WN = (NN >= 64) ? (NN/4) : NN;
  constexpr int MT = WM/16, NT = WN/16;
  const int tid = threadIdx.x;
  const int wave = tid >> 6, lane = tid & 63, quad = lane >> 4, cl = lane & 15;
  const int m0 = blockIdx.x * 64;
  const int wmo = (NN >= 64) ? 0 : wave*16;
  const int wno = (NN >= 64) ? wave*WN : 0;

  f32x4 zero = {0.f,0.f,0.f,0.f};
  f32x4 acc[MT][NT];
  #pragma unroll
  for (int i=0;i<MT;i++)
    #pragma unroll
    for (int j=0;j<NT;j++) acc[i][j] = zero;

  #pragma unroll
  for (int kc = 0; kc < KK/32; kc++){
    const int ko = kc*32 + quad*8;
    bf16x8 a[MT], b[NT];
    #pragma unroll
    for (int mt=0; mt<MT; mt++){
      int row = m0 + wmo + mt*16 + cl;
      a[mt] = *(const bf16x8*)((const short*)A0 + (long)row*KK + ko);
    }
    #pragma unroll
    for (int nt=0; nt<NT; nt++)
      b[nt] = *(const bf16x8*)(Bt + (long)(wno + nt*16 + cl)*KK + ko);
    #pragma unroll
    for (int mt=0; mt<MT; mt++)
      #pragma unroll
      for (int nt=0; nt<NT; nt++)
        acc[mt][nt] = mfma16(a[mt], b[nt], acc[mt][nt]);
  }
  #pragma unroll
  for (int mt=0; mt<MT; mt++){
    #pragma unroll
    for (int nt=0; nt<NT; nt++){
      int col = wno + nt*16 + cl;
      float bv = 0.f;
      if constexpr (BIAS) bv = bias[col];
      #pragma unroll
      for (int r=0;r<4;r++){
        int row = m0 + wmo + mt*16 + quad*4 + r;
        float v = acc[mt][nt][r] + bv;
        if (ACT==1) v = fmaxf(v, 0.f);
        if (ACT==2) v = (v > 0.f) ? v : expm1f(v);
        if constexpr (OUTF32) ((float*)Out)[(long)row*NN + col] = v;
        else ((short*)Out)[(long)row*NN + col] = f2bf(v);
      }
    }
  }
}

// ---- CSR build (both graphs fused per kernel) ----
__global__ void scan2_k(const int* __restrict__ deg1, int* __restrict__ rs1, int* __restrict__ cur1,
                        const int* __restrict__ deg2, int* __restrict__ rs2, int* __restrict__ cur2){
  const int* deg = blockIdx.x ? deg2 : deg1;
  int* rowstart = blockIdx.x ? rs2 : rs1;
  int* cursor = blockIdx.x ? cur2 : cur1;
  __shared__ int csum[256];
  __shared__ int base[257];
  int t = threadIdx.x;
  int loc[32];
  int s = 0;
  for (int j=0;j<32;j++){ int d = deg[t*32+j]; loc[j] = s; s += d; }
  csum[t] = s;
  __syncthreads();
  if (t==0){ int a=0; for (int i=0;i<256;i++){ base[i]=a; a+=csum[i]; } base[256]=a; }
  __syncthreads();
  for (int j=0;j<32;j++){ int v = base[t] + loc[j]; rowstart[t*32+j]=v; cursor[t*32+j]=v; }
  if (t==0) rowstart[NROWS] = base[256];
}
__global__ void fill2_k(const int* __restrict__ ei1, const float* __restrict__ w1, int* __restrict__ cur1,
                        int* __restrict__ ecol1, float* __restrict__ ew1,
                        const int* __restrict__ ei2, const float* __restrict__ w2, int* __restrict__ cur2,
                        int* __restrict__ ecol2, float* __restrict__ ew2){
  int b = blockIdx.x;
  bool g2 = (b >= NEDGE/256);
  const int* ei = g2 ? ei2 : ei1;
  const float* w = g2 ? w2 : w1;
  int* cursor = g2 ? cur2 : cur1;
  int* ecol = g2 ? ecol2 : ecol1;
  float* ew = g2 ? ew2 : ew1;
  int e = (b % (NEDGE/256))*256 + threadIdx.x;
  int r = ei[e];
  int p = atomicAdd(&cursor[r], 1);
  ecol[p] = ei[NEDGE + e];
  ew[p] = w[e];
}

// ---- GCN aggregation (gather form): 16-deep gather unroll for MLP ----
__device__ __forceinline__ void acc8(float* acc, int4 v, float f){
  const unsigned* u = (const unsigned*)&v;
  #pragma unroll
  for (int i=0;i<4;i++){
    union{unsigned x; float y;} lo, hi;
    lo.x = u[i] << 16;
    hi.x = u[i] & 0xffff0000u;
    acc[2*i]   = fmaf(f, lo.y, acc[2*i]);
    acc[2*i+1] = fmaf(f, hi.y, acc[2*i+1]);
  }
}

template<int C, bool RELU, bool HASB>
__global__ __launch_bounds__(256) void gather_k(const short* __restrict__ sup,
    const int* __restrict__ rs1, const int* __restrict__ ec1, const float* __restrict__ w1,
    const int* __restrict__ rs2, const int* __restrict__ ec2, const float* __restrict__ w2,
    const float* __restrict__ bias, short* __restrict__ out){
  constexpr int G = C/8;
  const int g = threadIdx.x % G;
  const int sub = threadIdx.x / G;
  const int row = blockIdx.x*(256/G) + sub;
  const int* rs; const int* ec; const float* w; int soff, lr;
  if (row < NROWS){ rs=rs1; ec=ec1; w=w1; soff=0; lr=row; }
  else            { rs=rs2; ec=ec2; w=w2; soff=NROWS; lr=row-NROWS; }
  const short* sb = sup + (long)soff*C + g*8;
  float acc[8];
  #pragma unroll
  for (int j=0;j<8;j++) acc[j] = HASB ? bias[g*8+j] : 0.f;
  const int s = rs[lr], e = rs[lr+1];
  int k = s;
  for (; k+16 <= e; k+=16){
    int c[16]; float f[16]; int4 v[16];
    #pragma unroll
    for (int u=0;u<16;u++){ c[u]=ec[k+u]; f[u]=w[k+u]; }
    #pragma unroll
    for (int u=0;u<16;u++) v[u] = *(const int4*)(sb + (long)c[u]*C);
    #pragma unroll
    for (int u=0;u<16;u++) acc8(acc, v[u], f[u]);
  }
  for (; k+4 <= e; k+=4){
    int c0=ec[k],c1=ec[k+1],c2=ec[k+2],c3=ec[k+3];
    float f0=w[k],f1=w[k+1],f2=w[k+2],f3=w[k+3];
    int4 v0 = *(const int4*)(sb + (long)c0*C);
    int4 v1 = *(const int4*)(sb + (long)c1*C);
    int4 v2 = *(const int4*)(sb + (long)c2*C);
    int4 v3 = *(const int4*)(sb + (long)c3*C);
    acc8(acc,v0,f0); acc8(acc,v1,f1); acc8(acc,v2,f2); acc8(acc,v3,f3);
  }
  for (; k < e; k++){
    int c0=ec[k]; float f0=w[k];
    int4 v0 = *(const int4*)(sb + (long)c0*C);
    acc8(acc,v0,f0);
  }
  int4 ov;
  unsigned* ou = (unsigned*)&ov;
  #pragma unroll
  for (int i=0;i<4;i++){
    float a0 = acc[2*i], a1 = acc[2*i+1];
    if (RELU){ a0 = fmaxf(a0,0.f); a1 = fmaxf(a1,0.f); }
    unsigned p0 = (unsigned)(unsigned short)f2bf(a0);
    unsigned p1 = (unsigned)(unsigned short)f2bf(a1);
    ou[i] = p0 | (p1<<16);
  }
  *(int4*)(out + (long)row*C + g*8) = ov;
}

// ---- normalize rows of z (fp32 [16384,128]) -> fp8 * sqrt(KE) in MFMA fragment
// order (Zf); bdot[i] = z1n_i . z2n_i (fp32, unscaled). ----
__global__ __launch_bounds__(256) void norm_k(const float* __restrict__ z, unsigned short* __restrict__ Zf,
                                              float* __restrict__ bdot){
  const float SQKE = 1.6986436f;   // sqrt(2*log2(e))
  int wave = threadIdx.x>>6, lane = threadIdx.x&63;
  int i = blockIdx.x*4 + wave;   // row pair (i, i+8192)
  float2 a2 = *(const float2*)(z + (long)i*128 + lane*2);
  float2 b2 = *(const float2*)(z + (long)(i+NROWS)*128 + lane*2);
  float sa = a2.x*a2.x + a2.y*a2.y;
  float sb = b2.x*b2.x + b2.y*b2.y;
  #pragma unroll
  for (int m=1;m<64;m<<=1){ sa += __shfl_xor(sa,m); sb += __shfl_xor(sb,m); }
  float ra = 1.f / fmaxf(sqrtf(sa), 1e-12f);
  float rb = 1.f / fmaxf(sqrtf(sb), 1e-12f);
  float ras = ra*SQKE, rbs = rb*SQKE;
  const int d = lane>>1, kc = d>>3, q = (d>>1)&3, j4 = d&1, h = lane&1;
  const int base = kc*128 + j4;
  {
    int r = i;
    long o = ((long)(r>>4)*512 + base + ((r&15)+16*q)*2)*2 + h;
    Zf[o] = pack2fp8(a2.x*ras, a2.y*ras);
  }
  {
    int r = i + NROWS;
    long o = ((long)(r>>4)*512 + base + ((r&15)+16*q)*2)*2 + h;
    Zf[o] = pack2fp8(b2.x*rbs, b2.y*rbs);
  }
  float dd = (a2.x*ra)*(b2.x*rb) + (a2.y*ra)*(b2.y*rb);
  #pragma unroll
  for (int m=1;m<64;m<<=1) dd += __shfl_xor(dd,m);
  if (lane==0) bdot[i] = dd;
}

// ---- symmetric exp-Gram partials: 128x128 LDS supertile, 8 waves x (32x64) tiles.
// Small acc (32 regs/wave) -> 5 waves/SIMD; cross-wave sums via LDS atomicAdd after
// 2-level shuffle pre-fold. UT over 128x128 supertile grid, diag = full supertile.
__global__ __launch_bounds__(512,2) void gram5_k(const unsigned char* __restrict__ Zf,
                                                 float* __restrict__ P){
  __shared__ __align__(16) unsigned char Zi[16384];
  __shared__ __align__(16) unsigned char Zj[16384];
  __shared__ float srow[128];
  __shared__ float scol[128];
  const int t = blockIdx.x;
  int ti = (int)((257.0f - sqrtf(257.0f*257.0f - 8.0f*(float)t))*0.5f);
  while ((ti+1)*128 - ((ti+1)*ti)/2 <= t) ti++;
  while (ti*128 - (ti*(ti-1))/2 > t) ti--;
  const int tj = ti + (t - (ti*128 - (ti*(ti-1))/2));
  const bool diag = (ti==tj);
  const int tid = threadIdx.x;
  if (tid < 128) srow[tid] = 0.f;
  else if (tid < 256) scol[tid-128] = 0.f;
  {
    const int4* srcA = (const int4*)(Zf + (long)ti*16384);
    int4* dA = (int4*)Zi;
    dA[tid] = srcA[tid];
    dA[512+tid] = srcA[512+tid];
    if (!diag){
      const int4* srcB = (const int4*)(Zf + (long)tj*16384);
      int4* dB = (int4*)Zj;
      dB[tid] = srcB[tid];
      dB[512+tid] = srcB[512+tid];
    }
  }
  __syncthreads();
  const unsigned char* Bs = diag ? Zi : Zj;
  const int wave = tid>>6, lane = tid&63;
  const int qr = wave>>1, qc = wave&1;           // 4 row-strips x 2 col-halves
  const unsigned char* za = Zi + qr*2*2048 + lane*8;
  const unsigned char* zb = Bs + qc*4*2048 + lane*8;

  f32x4 zero = {0.f,0.f,0.f,0.f};
  f32x4 acc[2][4];
  #pragma unroll
  for (int i=0;i<2;i++)
    #pragma unroll
    for (int j=0;j<4;j++) acc[i][j]=zero;

  i64 aA[2], bA[4], aB[2], bB[4];
  #pragma unroll
  for (int x=0;x<2;x++) aA[x] = *(const i64*)(za + x*2048);
  #pragma unroll
  for (int x=0;x<4;x++) bA[x] = *(const i64*)(zb + x*2048);
  #pragma unroll
  for (int kc=0;kc<4;kc++){
    i64* ac = (kc&1) ? aB : aA;
    i64* bc = (kc&1) ? bB : bA;
    i64* an = (kc&1) ? aA : aB;
    i64* bn = (kc&1) ? bA : bB;
    if (kc<3){
      #pragma unroll
      for (int x=0;x<2;x++) an[x] = *(const i64*)(za + x*2048 + (kc+1)*512);
      #pragma unroll
      for (int x=0;x<4;x++) bn[x] = *(const i64*)(zb + x*2048 + (kc+1)*512);
    }
    #pragma unroll
    for (int mt=0;mt<2;mt++)
      #pragma unroll
      for (int nt=0;nt<4;nt++)
        acc[mt][nt] = __builtin_amdgcn_mfma_f32_16x16x32_fp8_fp8(ac[mt], bc[nt], acc[mt][nt], 0, 0, 0);
  }

  const int quad = lane>>4, cl = lane&15;
  f32x2 z2 = {0.f,0.f};
  f32x2 rs01[2] = {z2,z2}, rs23[2] = {z2,z2};
  f32x2 cs[4] = {z2,z2,z2,z2};
  #pragma unroll
  for (int mt=0;mt<2;mt++){
    #pragma unroll
    for (int nt=0;nt<4;nt++){
      f32x4 v = acc[mt][nt];
      float e0 = fexp2(v[0]), e1 = fexp2(v[1]);
      float e2 = fexp2(v[2]), e3 = fexp2(v[3]);
      f32x2 p01 = {e0,e1}, p23 = {e2,e3};
      rs01[mt] += p01; rs23[mt] += p23;
      cs[nt] += p01; cs[nt] += p23;
    }
  }
  // rows: fold over cl bits 0,1 (4 lanes remain per quad), then LDS atomics (4-way)
  #pragma unroll
  for (int mt=0;mt<2;mt++){
    union{f32x2 v; double d;} u0, u1;
    u0.v = rs01[mt]; u1.v = rs23[mt];
    #pragma unroll
    for (int m=1;m<4;m<<=1){
      union{double d; f32x2 v;} o0, o1;
      o0.d = __shfl_xor(u0.d, m); o1.d = __shfl_xor(u1.d, m);
      u0.v += o0.v; u1.v += o1.v;
    }
    if ((cl&3)==0){
      int rb = qr*32 + mt*16 + quad*4;
      atomicAdd(&srow[rb+0], u0.v.x);
      atomicAdd(&srow[rb+1], u0.v.y);
      atomicAdd(&srow[rb+2], u1.v.x);
      atomicAdd(&srow[rb+3], u1.v.y);
    }
  }
  // cols (mirror) for off-diagonal: 4-way contention across quads
  if (!diag){
    #pragma unroll
    for (int nt=0;nt<4;nt++){
      float s = cs[nt].x + cs[nt].y;
      atomicAdd(&scol[qc*64 + nt*16 + cl], s);
    }
  }
  __syncthreads();
  if (tid < 128){
    P[((long)ti*128 + tj)*128 + tid] = srow[tid];
  } else if (tid < 256 && !diag){
    int c = tid - 128;
    P[((long)tj*128 + ti)*128 + c] = scol[c];
  }
}

// ---- fused final reduce + loss: thread owns pair (i, i+8192), sums both P slices,
// computes log terms, block-reduce, atomicAdd into pre-zeroed d_out. ----
__global__ void rloss_k(const float* __restrict__ P, const float* __restrict__ bdot,
                        float* __restrict__ out){
  __shared__ float red[256];
  const float E2 = 7.3890560989306495f;  // exp(2) = diag(refl)
  int t = threadIdx.x;
  int i = blockIdx.x*256 + t;            // 0..8191
  int j = i + NROWS;
  const float* p1 = P + (long)(i>>7)*128*128 + (i&127);
  const float* p2 = P + (long)(j>>7)*128*128 + (j&127);
  float s1 = 0.f, s2 = 0.f;
  #pragma unroll 8
  for (int b=0;b<128;b++){ s1 += p1[b*128]; s2 += p2[b*128]; }
  float lb = 2.f * bdot[i];
  float term = 0.5f * ((logf(s1 - E2) - lb) + (logf(s2 - E2) - lb));
  red[t]=term; __syncthreads();
  for (int st=128; st>0; st>>=1){ if (t<st) red[t]+=red[t+st]; __syncthreads(); }
  if (t==0) atomicAdd(out, red[0] / (float)NROWS);
}

extern "C" void kernel_launch(void* const* d_in, const int* in_sizes, int n_in,
                              void* d_out, int out_size, void* d_ws, size_t ws_size,
                              hipStream_t stream){
  const float* feat1 = (const float*)d_in[0];
  const float* feat2 = (const float*)d_in[1];
  const int*   ei1   = (const int*)d_in[2];
  const float* w1    = (const float*)d_in[3];
  const int*   ei2   = (const int*)d_in[4];
  const float* w2    = (const float*)d_in[5];
  const float* w_l1a = (const float*)d_in[6];
  const float* b_l1a = (const float*)d_in[7];
  const float* w_l1b = (const float*)d_in[8];
  const float* b_l1b = (const float*)d_in[9];
  const float* w_g1  = (const float*)d_in[10];
  const float* b_g1  = (const float*)d_in[11];
  const float* w_g2  = (const float*)d_in[12];
  const float* b_g2  = (const float*)d_in[13];
  const float* w_fc1 = (const float*)d_in[14];
  const float* b_fc1 = (const float*)d_in[15];
  const float* w_fc2 = (const float*)d_in[16];
  const float* b_fc2 = (const float*)d_in[17];

  char* base = (char*)d_ws;
  size_t off = 0;
  auto alloc = [&](size_t bytes)->void*{
    void* r = base + off;
    off = (off + bytes + 255) & ~(size_t)255;
    return r;
  };
  // P (8MB) aliases z's region [0,8M) — z is dead after norm_k, before gram5_k.
  float* z    = (float*)alloc((size_t)MROWS*128*4);                 // [0,8M)
  short* a1   = (short*)alloc((size_t)MROWS*64*2);
  short* xb   = (short*)alloc((size_t)MROWS*32*2);
  short* ax   = (short*)alloc((size_t)MROWS*32*2);
  short* hb   = (short*)alloc((size_t)MROWS*256*2);
  short* s2   = (short*)alloc((size_t)MROWS*128*2);
  short* hh   = (short*)alloc((size_t)MROWS*128*2);
  short* t2   = (short*)alloc((size_t)MROWS*64*2);
  short* wl1a_t = (short*)alloc(512*64*2);
  short* wl1b_t = (short*)alloc(64*32*2);
  short* wg1_t  = (short*)alloc(32*256*2);
  short* wg2_t  = (short*)alloc(256*128*2);
  short* wfc1_t = (short*)alloc(128*64*2);
  short* wfc2_t = (short*)alloc(64*128*2);
  unsigned short* Zf = (unsigned short*)alloc((size_t)MROWS*128);   // fragment-order fp8 (2MB)
  int*   deg1 = (int*)alloc(NROWS*4);                               // zeroed pair
  int*   deg2 = (int*)alloc(NROWS*4);
  int* rs1  = (int*)alloc((NROWS+1)*4);
  int* cur1 = (int*)alloc(NROWS*4);
  int* rs2  = (int*)alloc((NROWS+1)*4);
  int* cur2 = (int*)alloc(NROWS*4);
  int*   ecol1 = (int*)alloc((size_t)NEDGE*4);
  float* ewt1  = (float*)alloc((size_t)NEDGE*4);
  int*   ecol2 = (int*)alloc((size_t)NEDGE*4);
  float* ewt2  = (float*)alloc((size_t)NEDGE*4);
  float* bdot  = (float*)alloc(NROWS*4);
  short* fb    = (short*)alloc((size_t)MROWS*512*2);                // bf16 feats (16MB)
  float* P = (float*)d_ws;   // 8MB alias over z (see note)

  hipMemsetAsync(deg1, 0, (size_t)2*NROWS*4, stream);
  hipMemsetAsync(d_out, 0, sizeof(float), stream);

  WtArgs wa;
  wa.src[0]=w_l1a; wa.dst[0]=wl1a_t; wa.K[0]=512; wa.N[0]=64;
  wa.src[1]=w_l1b; wa.dst[1]=wl1b_t; wa.K[1]=64;  wa.N[1]=32;
  wa.src[2]=w_g1;  wa.dst[2]=wg1_t;  wa.K[2]=32;  wa.N[2]=256;
  wa.src[3]=w_g2;  wa.dst[3]=wg2_t;  wa.K[3]=256; wa.N[3]=128;
  wa.src[4]=w_fc1; wa.dst[4]=wfc1_t; wa.K[4]=128; wa.N[4]=64;
  wa.src[5]=w_fc2; wa.dst[5]=wfc2_t; wa.K[5]=64;  wa.N[5]=128;
  wa.off[0]=0;
  for (int i=0;i<6;i++) wa.off[i+1] = wa.off[i] + wa.K[i]*wa.N[i];
  wa.nwt = (wa.off[6]+255)/256;
  const int ncvt = MROWS*512/4/256;   // 8192
  setup_k<<<wa.nwt + 2*(NEDGE/256) + ncvt,256,0,stream>>>(wa, ei1, ei2, deg1, deg2,
                                                          feat1, feat2, fb);
  scan2_k<<<2,256,0,stream>>>(deg1, rs1, cur1, deg2, rs2, cur2);
  fill2_k<<<2*(NEDGE/256),256,0,stream>>>(ei1, w1, cur1, ecol1, ewt1,
                                          ei2, w2, cur2, ecol2, ewt2);

  // encoder (both graphs batched: rows 0..8191 = view1, 8192..16383 = view2)
  gemm_k<64,512,1,true,false><<<MROWS/64,256,0,stream>>>(fb, wl1a_t, b_l1a, a1);
  gemm_k<32,64,0,true,false><<<MROWS/64,256,0,stream>>>(a1, wl1b_t, b_l1b, xb);
  // layer 1: aggregate FIRST in 32-dim space (adj@(x@W) == (adj@x)@W)
  gather_k<32,false,false><<<MROWS/64,256,0,stream>>>(xb, rs1,ecol1,ewt1, rs2,ecol2,ewt2, nullptr, ax);
  gemm_k<256,32,1,true,false><<<MROWS/64,256,0,stream>>>(ax, wg1_t, b_g1, hb);
  // layer 2: GEMM then aggregate (128 < 256 wide)
  gemm_k<128,256,0,false,false><<<MROWS/64,256,0,stream>>>(hb, wg2_t, nullptr, s2);
  gather_k<128,false,true><<<MROWS/16,256,0,stream>>>(s2, rs1,ecol1,ewt1, rs2,ecol2,ewt2, b_g2, hh);
  // projection
  gemm_k<64,128,2,true,false><<<MROWS/64,256,0,stream>>>(hh, wfc1_t, b_fc1, t2);
  gemm_k<128,64,0,true,true><<<MROWS/64,256,0,stream>>>(t2, wfc2_t, b_fc2, z);

  norm_k<<<NROWS/4,256,0,stream>>>(z, Zf, bdot);

  gram5_k<<<8256,512,0,stream>>>((const unsigned char*)Zf, P);   // UT of 128^2 supertiles
  rloss_k<<<NROWS/256,256,0,stream>>>(P, bdot, (float*)d_out);
}

// Round 12
// 287.582 us; speedup vs baseline: 1.4195x; 1.4195x over previous
//
#include <hip/hip_runtime.h>
#include <hip/hip_bf16.h>
#include <math.h>

// GRACE-style graph contrastive loss, MI355X (gfx950).
// R12 (= R11 resubmit after GPU acquisition timeout; g34_k bias line cleaned).
// gram = R8 gram3 (proven 55us; R10's LDS fp32 atomicAdd = CAS loop -> 174us).
// Fusions: mlp12_k (feat fp32 -> 64 relu -> LDS -> 32, kills featcvt pass + fb),
// g34_k (32 -> 256 relu -> LDS -> 128, hb never hits HBM). 14 dispatches.

#define NROWS 8192
#define MROWS 16384
#define NEDGE 262144

typedef __attribute__((ext_vector_type(8))) short bf16x8;
typedef __attribute__((ext_vector_type(4))) float f32x4;
typedef __attribute__((ext_vector_type(2))) float f32x2;
typedef long long i64;

__device__ __forceinline__ short f2bf(float f){
  union { float f; unsigned u; } cv; cv.f = f;
  unsigned u = cv.u;
  unsigned r = (u + 0x7fffu + ((u >> 16) & 1u)) >> 16;  // RNE; inputs finite
  return (short)r;
}
__device__ __forceinline__ f32x4 mfma16(bf16x8 a, bf16x8 b, f32x4 c){
  return __builtin_amdgcn_mfma_f32_16x16x32_bf16(a, b, c, 0, 0, 0);
}
__device__ __forceinline__ float fexp2(float x){
#if __has_builtin(__builtin_amdgcn_exp2f)
  return __builtin_amdgcn_exp2f(x);   // raw v_exp_f32; args bounded |x|<3
#else
  return exp2f(x);
#endif
}

// ---- fp8 e4m3fn pack (RNE) ----
__device__ unsigned char f2e4m3_sw(float f){
  float a = fabsf(f);
  unsigned s = (__float_as_uint(f)>>24)&0x80u;
  if (!(a>0.f)) return (unsigned char)s;
  if (a>448.f) a=448.f;
  int e; frexpf(a,&e);
  int eff=e-1;
  unsigned code;
  if (eff<-6){
    float q=rintf(a*512.f);
    code=(unsigned)q; if(code>7)code=7;
  } else {
    float q=rintf(a*exp2f((float)(3-eff)));
    unsigned mant=(unsigned)q;
    if(mant>=16){mant=8;eff++;}
    if(eff>8) return (unsigned char)(s|0x7e);
    code=((unsigned)(eff+7)<<3)|(mant-8);
  }
  return (unsigned char)(s|code);
}
__device__ __forceinline__ unsigned short pack2fp8(float a, float b){
#if __has_builtin(__builtin_amdgcn_cvt_pk_fp8_f32)
  int v = __builtin_amdgcn_cvt_pk_fp8_f32(a, b, 0, false);
  return (unsigned short)(v & 0xffff);
#else
  return (unsigned short)((unsigned)f2e4m3_sw(a) | ((unsigned)f2e4m3_sw(b)<<8));
#endif
}

// ---- fused setup: weight transpose+bf16 | degree histogram ----
struct WtArgs {
  const float* src[6];
  short* dst[6];
  int K[6], N[6];
  int off[7];
  int nwt;
};
__global__ void setup_k(WtArgs a, const int* __restrict__ ei1, const int* __restrict__ ei2,
                        int* __restrict__ deg1, int* __restrict__ deg2){
  int b = blockIdx.x;
  if (b < a.nwt){
    int i = b*256 + threadIdx.x;
    if (i >= a.off[6]) return;
    int s = 0;
    #pragma unroll
    for (int j=1;j<6;j++) if (i >= a.off[j]) s=j;
    int l = i - a.off[s];
    int K=a.K[s], N=a.N[s];
    int k=l/N, n=l-k*N;
    a.dst[s][(long)n*K+k] = f2bf(a.src[s][l]);
  } else {
    int hb = b - a.nwt;
    const int* ei = (hb < NEDGE/256) ? ei1 : ei2;
    int* deg = (hb < NEDGE/256) ? deg1 : deg2;
    int e = (hb % (NEDGE/256))*256 + threadIdx.x;
    atomicAdd(&deg[ei[e]], 1);
  }
}

// ---- fused MLP layer1: xb[M,32] = (relu(feat@Wa + ba))@Wb + bb ----
// Stage1 (NN=64, K=512, fp32 A inline-cvt) -> LDS tile -> Stage2 (NN=32, K=64).
__global__ __launch_bounds__(256) void mlp12_k(const float* __restrict__ F0, const float* __restrict__ F1,
                                               const short* __restrict__ Wa, const float* __restrict__ ba,
                                               const short* __restrict__ Wb, const float* __restrict__ bb,
                                               short* __restrict__ xb){
  __shared__ short a1s[64*72];   // 64x64 tile, +8 pad
  const int tid = threadIdx.x;
  const int wave = tid>>6, lane = tid&63, quad = lane>>4, cl = lane&15;
  const int m0 = blockIdx.x*64;
  const int wno = wave*16;       // stage1: NT=1, col slab of 16

  f32x4 zero = {0.f,0.f,0.f,0.f};
  f32x4 acc[4];
  #pragma unroll
  for (int i=0;i<4;i++) acc[i]=zero;
  #pragma unroll
  for (int kc=0;kc<16;kc++){
    const int ko = kc*32 + quad*8;
    bf16x8 a[4], b;
    #pragma unroll
    for (int mt=0;mt<4;mt++){
      int row = m0 + mt*16 + cl;
      const float* ar = (row < NROWS) ? (F0 + (long)row*512 + ko)
                                      : (F1 + (long)(row-NROWS)*512 + ko);
      float4 f0 = *(const float4*)ar;
      float4 f1 = *(const float4*)(ar+4);
      bf16x8 t;
      t[0]=f2bf(f0.x); t[1]=f2bf(f0.y); t[2]=f2bf(f0.z); t[3]=f2bf(f0.w);
      t[4]=f2bf(f1.x); t[5]=f2bf(f1.y); t[6]=f2bf(f1.z); t[7]=f2bf(f1.w);
      a[mt]=t;
    }
    b = *(const bf16x8*)(Wa + (long)(wno + cl)*512 + ko);
    #pragma unroll
    for (int mt=0;mt<4;mt++) acc[mt] = mfma16(a[mt], b, acc[mt]);
  }
  {
    int col = wno + cl;
    float bv = ba[col];
    #pragma unroll
    for (int mt=0;mt<4;mt++)
      #pragma unroll
      for (int r=0;r<4;r++){
        int row = mt*16 + quad*4 + r;
        a1s[row*72 + col] = f2bf(fmaxf(acc[mt][r] + bv, 0.f));
      }
  }
  __syncthreads();
  // stage2: wave owns 16-row strip, NT=2 (full 32 cols), K=64
  const int wmo = wave*16;
  f32x4 acc2[2] = {zero, zero};
  #pragma unroll
  for (int kc=0;kc<2;kc++){
    const int ko = kc*32 + quad*8;
    bf16x8 a = *(const bf16x8*)&a1s[(wmo+cl)*72 + ko];
    #pragma unroll
    for (int nt=0;nt<2;nt++){
      bf16x8 b = *(const bf16x8*)(Wb + (long)(nt*16 + cl)*64 + ko);
      acc2[nt] = mfma16(a, b, acc2[nt]);
    }
  }
  #pragma unroll
  for (int nt=0;nt<2;nt++){
    int col = nt*16 + cl;
    float bv = bb[col];
    #pragma unroll
    for (int r=0;r<4;r++){
      int row = wmo + quad*4 + r;
      xb[(long)(m0+row)*32 + col] = f2bf(acc2[nt][r] + bv);
    }
  }
}

// ---- fused GCN mid: s2[M,128] = (relu(ax@Wg1 + bg1))@Wg2 ----
// Stage1 (NN=256, K=32) -> 33KB LDS tile -> Stage2 (NN=128, K=256).
__global__ __launch_bounds__(256) void g34_k(const short* __restrict__ ax,
                                             const short* __restrict__ Wg1, const float* __restrict__ bg1,
                                             const short* __restrict__ Wg2,
                                             short* __restrict__ s2){
  __shared__ short hbs[64*264];   // 64x256 tile, +8 pad
  const int tid = threadIdx.x;
  const int wave = tid>>6, lane = tid&63, quad = lane>>4, cl = lane&15;
  const int m0 = blockIdx.x*64;
  {
    const int wno = wave*64;   // stage1: NT=4
    f32x4 zero = {0.f,0.f,0.f,0.f};
    f32x4 acc[4][4];
    #pragma unroll
    for (int i=0;i<4;i++)
      #pragma unroll
      for (int j=0;j<4;j++) acc[i][j]=zero;
    const int ko = quad*8;     // K=32: single kc
    bf16x8 a[4], b[4];
    #pragma unroll
    for (int mt=0;mt<4;mt++)
      a[mt] = *(const bf16x8*)(ax + (long)(m0 + mt*16 + cl)*32 + ko);
    #pragma unroll
    for (int nt=0;nt<4;nt++)
      b[nt] = *(const bf16x8*)(Wg1 + (long)(wno + nt*16 + cl)*32 + ko);
    #pragma unroll
    for (int mt=0;mt<4;mt++)
      #pragma unroll
      for (int nt=0;nt<4;nt++)
        acc[mt][nt] = mfma16(a[mt], b[nt], acc[mt][nt]);
    #pragma unroll
    for (int nt=0;nt<4;nt++){
      int col = wno + nt*16 + cl;
      float bv = bg1[col];
      #pragma unroll
      for (int mt=0;mt<4;mt++)
        #pragma unroll
        for (int r=0;r<4;r++){
          int row = mt*16 + quad*4 + r;
          hbs[row*264 + col] = f2bf(fmaxf(acc[mt][nt][r] + bv, 0.f));
        }
    }
  }
  __syncthreads();
  {
    const int wno = wave*32;   // stage2: NT=2, K=256
    f32x4 zero = {0.f,0.f,0.f,0.f};
    f32x4 acc[4][2];
    #pragma unroll
    for (int i=0;i<4;i++){ acc[i][0]=zero; acc[i][1]=zero; }
    #pragma unroll
    for (int kc=0;kc<8;kc++){
      const int ko = kc*32 + quad*8;
      bf16x8 a[4], b[2];
      #pragma unroll
      for (int mt=0;mt<4;mt++)
        a[mt] = *(const bf16x8*)&hbs[(mt*16+cl)*264 + ko];
      #pragma unroll
      for (int nt=0;nt<2;nt++)
        b[nt] = *(const bf16x8*)(Wg2 + (long)(wno + nt*16 + cl)*256 + ko);
      #pragma unroll
      for (int mt=0;mt<4;mt++)
        #pragma unroll
        for (int nt=0;nt<2;nt++)
          acc[mt][nt] = mfma16(a[mt], b[nt], acc[mt][nt]);
    }
    #pragma unroll
    for (int mt=0;mt<4;mt++)
      #pragma unroll
      for (int nt=0;nt<2;nt++){
        int col = wno + nt*16 + cl;
        #pragma unroll
        for (int r=0;r<4;r++){
          int row = mt*16 + quad*4 + r;
          s2[(long)(m0+row)*128 + col] = f2bf(acc[mt][nt][r]);
        }
      }
  }
}

// ---- generic tall-skinny MFMA GEMM (projection layers) ----
template<int NN, int KK, int ACT, bool BIAS, bool OUTF32>
__global__ __launch_bounds__(256) void gemm_k(const void* __restrict__ A0,
                                              const short* __restrict__ Bt, const float* __restrict__ bias,
                                              void* __restrict__ Out){
  constexpr int WM = (NN >= 64) ? 64 : 16;
  constexpr int WN = (NN >= 64) ? (NN/4) : NN;
  constexpr int MT = WM/16, NT = WN/16;
  const int tid = threadIdx.x;
  const int wave = tid >> 6, lane = tid & 63, quad = lane >> 4, cl = lane & 15;
  const int m0 = blockIdx.x * 64;
  const int wmo = (NN >= 64) ? 0 : wave*16;
  const int wno = (NN >= 64) ? wave*WN : 0;

  f32x4 zero = {0.f,0.f,0.f,0.f};
  f32x4 acc[MT][NT];
  #pragma unroll
  for (int i=0;i<MT;i++)
    #pragma unroll
    for (int j=0;j<NT;j++) acc[i][j] = zero;

  #pragma unroll
  for (int kc = 0; kc < KK/32; kc++){
    const int ko = kc*32 + quad*8;
    bf16x8 a[MT], b[NT];
    #pragma unroll
    for (int mt=0; mt<MT; mt++){
      int row = m0 + wmo + mt*16 + cl;
      a[mt] = *(const bf16x8*)((const short*)A0 + (long)row*KK + ko);
    }
    #pragma unroll
    for (int nt=0; nt<NT; nt++)
      b[nt] = *(const bf16x8*)(Bt + (long)(wno + nt*16 + cl)*KK + ko);
    #pragma unroll
    for (int mt=0; mt<MT; mt++)
      #pragma unroll
      for (int nt=0; nt<NT; nt++)
        acc[mt][nt] = mfma16(a[mt], b[nt], acc[mt][nt]);
  }
  #pragma unroll
  for (int mt=0; mt<MT; mt++){
    #pragma unroll
    for (int nt=0; nt<NT; nt++){
      int col = wno + nt*16 + cl;
      float bv = 0.f;
      if constexpr (BIAS) bv = bias[col];
      #pragma unroll
      for (int r=0;r<4;r++){
        int row = m0 + wmo + mt*16 + quad*4 + r;
        float v = acc[mt][nt][r] + bv;
        if (ACT==1) v = fmaxf(v, 0.f);
        if (ACT==2) v = (v > 0.f) ? v : expm1f(v);
        if constexpr (OUTF32) ((float*)Out)[(long)row*NN + col] = v;
        else ((short*)Out)[(long)row*NN + col] = f2bf(v);
      }
    }
  }
}

// ---- CSR build ----
__global__ void scan2_k(const int* __restrict__ deg1, int* __restrict__ rs1, int* __restrict__ cur1,
                        const int* __restrict__ deg2, int* __restrict__ rs2, int* __restrict__ cur2){
  const int* deg = blockIdx.x ? deg2 : deg1;
  int* rowstart = blockIdx.x ? rs2 : rs1;
  int* cursor = blockIdx.x ? cur2 : cur1;
  __shared__ int csum[256];
  __shared__ int base[257];
  int t = threadIdx.x;
  int loc[32];
  int s = 0;
  for (int j=0;j<32;j++){ int d = deg[t*32+j]; loc[j] = s; s += d; }
  csum[t] = s;
  __syncthreads();
  if (t==0){ int a=0; for (int i=0;i<256;i++){ base[i]=a; a+=csum[i]; } base[256]=a; }
  __syncthreads();
  for (int j=0;j<32;j++){ int v = base[t] + loc[j]; rowstart[t*32+j]=v; cursor[t*32+j]=v; }
  if (t==0) rowstart[NROWS] = base[256];
}
__global__ void fill2_k(const int* __restrict__ ei1, const float* __restrict__ w1, int* __restrict__ cur1,
                        int* __restrict__ ecol1, float* __restrict__ ew1,
                        const int* __restrict__ ei2, const float* __restrict__ w2, int* __restrict__ cur2,
                        int* __restrict__ ecol2, float* __restrict__ ew2){
  int b = blockIdx.x;
  bool g2 = (b >= NEDGE/256);
  const int* ei = g2 ? ei2 : ei1;
  const float* w = g2 ? w2 : w1;
  int* cursor = g2 ? cur2 : cur1;
  int* ecol = g2 ? ecol2 : ecol1;
  float* ew = g2 ? ew2 : ew1;
  int e = (b % (NEDGE/256))*256 + threadIdx.x;
  int r = ei[e];
  int p = atomicAdd(&cursor[r], 1);
  ecol[p] = ei[NEDGE + e];
  ew[p] = w[e];
}

// ---- GCN aggregation (gather form): 16-deep gather unroll for MLP ----
__device__ __forceinline__ void acc8(float* acc, int4 v, float f){
  const unsigned* u = (const unsigned*)&v;
  #pragma unroll
  for (int i=0;i<4;i++){
    union{unsigned x; float y;} lo, hi;
    lo.x = u[i] << 16;
    hi.x = u[i] & 0xffff0000u;
    acc[2*i]   = fmaf(f, lo.y, acc[2*i]);
    acc[2*i+1] = fmaf(f, hi.y, acc[2*i+1]);
  }
}

template<int C, bool RELU, bool HASB>
__global__ __launch_bounds__(256) void gather_k(const short* __restrict__ sup,
    const int* __restrict__ rs1, const int* __restrict__ ec1, const float* __restrict__ w1,
    const int* __restrict__ rs2, const int* __restrict__ ec2, const float* __restrict__ w2,
    const float* __restrict__ bias, short* __restrict__ out){
  constexpr int G = C/8;
  const int g = threadIdx.x % G;
  const int sub = threadIdx.x / G;
  const int row = blockIdx.x*(256/G) + sub;
  const int* rs; const int* ec; const float* w; int soff, lr;
  if (row < NROWS){ rs=rs1; ec=ec1; w=w1; soff=0; lr=row; }
  else            { rs=rs2; ec=ec2; w=w2; soff=NROWS; lr=row-NROWS; }
  const short* sb = sup + (long)soff*C + g*8;
  float acc[8];
  #pragma unroll
  for (int j=0;j<8;j++) acc[j] = HASB ? bias[g*8+j] : 0.f;
  const int s = rs[lr], e = rs[lr+1];
  int k = s;
  for (; k+16 <= e; k+=16){
    int c[16]; float f[16]; int4 v[16];
    #pragma unroll
    for (int u=0;u<16;u++){ c[u]=ec[k+u]; f[u]=w[k+u]; }
    #pragma unroll
    for (int u=0;u<16;u++) v[u] = *(const int4*)(sb + (long)c[u]*C);
    #pragma unroll
    for (int u=0;u<16;u++) acc8(acc, v[u], f[u]);
  }
  for (; k+4 <= e; k+=4){
    int c0=ec[k],c1=ec[k+1],c2=ec[k+2],c3=ec[k+3];
    float f0=w[k],f1=w[k+1],f2=w[k+2],f3=w[k+3];
    int4 v0 = *(const int4*)(sb + (long)c0*C);
    int4 v1 = *(const int4*)(sb + (long)c1*C);
    int4 v2 = *(const int4*)(sb + (long)c2*C);
    int4 v3 = *(const int4*)(sb + (long)c3*C);
    acc8(acc,v0,f0); acc8(acc,v1,f1); acc8(acc,v2,f2); acc8(acc,v3,f3);
  }
  for (; k < e; k++){
    int c0=ec[k]; float f0=w[k];
    int4 v0 = *(const int4*)(sb + (long)c0*C);
    acc8(acc,v0,f0);
  }
  int4 ov;
  unsigned* ou = (unsigned*)&ov;
  #pragma unroll
  for (int i=0;i<4;i++){
    float a0 = acc[2*i], a1 = acc[2*i+1];
    if (RELU){ a0 = fmaxf(a0,0.f); a1 = fmaxf(a1,0.f); }
    unsigned p0 = (unsigned)(unsigned short)f2bf(a0);
    unsigned p1 = (unsigned)(unsigned short)f2bf(a1);
    ou[i] = p0 | (p1<<16);
  }
  *(int4*)(out + (long)row*C + g*8) = ov;
}

// ---- normalize rows of z (fp32 [16384,128]) -> fp8 * sqrt(KE) in MFMA fragment
// order (Zf); bdot[i] = z1n_i . z2n_i (fp32, unscaled). ----
__global__ __launch_bounds__(256) void norm_k(const float* __restrict__ z, unsigned short* __restrict__ Zf,
                                              float* __restrict__ bdot){
  const float SQKE = 1.6986436f;   // sqrt(2*log2(e))
  int wave = threadIdx.x>>6, lane = threadIdx.x&63;
  int i = blockIdx.x*4 + wave;   // row pair (i, i+8192)
  float2 a2 = *(const float2*)(z + (long)i*128 + lane*2);
  float2 b2 = *(const float2*)(z + (long)(i+NROWS)*128 + lane*2);
  float sa = a2.x*a2.x + a2.y*a2.y;
  float sb = b2.x*b2.x + b2.y*b2.y;
  #pragma unroll
  for (int m=1;m<64;m<<=1){ sa += __shfl_xor(sa,m); sb += __shfl_xor(sb,m); }
  float ra = 1.f / fmaxf(sqrtf(sa), 1e-12f);
  float rb = 1.f / fmaxf(sqrtf(sb), 1e-12f);
  float ras = ra*SQKE, rbs = rb*SQKE;
  const int d = lane>>1, kc = d>>3, q = (d>>1)&3, j4 = d&1, h = lane&1;
  const int base = kc*128 + j4;
  {
    int r = i;
    long o = ((long)(r>>4)*512 + base + ((r&15)+16*q)*2)*2 + h;
    Zf[o] = pack2fp8(a2.x*ras, a2.y*ras);
  }
  {
    int r = i + NROWS;
    long o = ((long)(r>>4)*512 + base + ((r&15)+16*q)*2)*2 + h;
    Zf[o] = pack2fp8(b2.x*rbs, b2.y*rbs);
  }
  float dd = (a2.x*ra)*(b2.x*rb) + (a2.y*ra)*(b2.y*rb);
  #pragma unroll
  for (int m=1;m<64;m<<=1) dd += __shfl_xor(dd,m);
  if (lane==0) bdot[i] = dd;
}

// ---- LDS-free symmetric exp-Gram partials (R8 gram3, proven 55us).
// One 64x64 tile per WAVE over UT of 256x256 tile grid. Inputs pre-scaled by
// sqrt(KE): epilogue is raw exp2. (256,4): do NOT raise floor (R7 spill lesson).
__global__ __launch_bounds__(256,4) void gram3_k(const unsigned char* __restrict__ Zf,
                                                 float* __restrict__ P){
  __shared__ float srow[4][64];
  __shared__ float scol[4][64];
  const int wave = threadIdx.x>>6, lane = threadIdx.x&63;
  const int t = blockIdx.x*4 + wave;           // UT tile index, T=256
  int ti = (int)((513.0f - sqrtf(513.0f*513.0f - 8.0f*(float)t))*0.5f);
  while ((ti+1)*256 - ((ti+1)*ti)/2 <= t) ti++;
  while (ti*256 - (ti*(ti-1))/2 > t) ti--;
  const int tj = ti + (t - (ti*256 - (ti*(ti-1))/2));
  const unsigned char* za = Zf + (long)ti*16*512 + lane*8;
  const unsigned char* zb = Zf + (long)tj*16*512 + lane*8;

  f32x4 zero = {0.f,0.f,0.f,0.f};
  f32x4 acc[4][4];
  #pragma unroll
  for (int i=0;i<4;i++)
    #pragma unroll
    for (int j=0;j<4;j++) acc[i][j]=zero;

  i64 aA[4], bA[4], aB[4], bB[4];
  #pragma unroll
  for (int x=0;x<4;x++){
    aA[x] = *(const i64*)(za + (x*4+0)*512);
    bA[x] = *(const i64*)(zb + (x*4+0)*512);
  }
  #pragma unroll
  for (int kc=0;kc<4;kc++){
    i64* ac = (kc&1) ? aB : aA;
    i64* bc = (kc&1) ? bB : bA;
    i64* an = (kc&1) ? aA : aB;
    i64* bn = (kc&1) ? bA : bB;
    if (kc<3){
      #pragma unroll
      for (int x=0;x<4;x++){
        an[x] = *(const i64*)(za + (x*4+kc+1)*512);
        bn[x] = *(const i64*)(zb + (x*4+kc+1)*512);
      }
    }
    #pragma unroll
    for (int mt=0;mt<4;mt++)
      #pragma unroll
      for (int nt=0;nt<4;nt++)
        acc[mt][nt] = __builtin_amdgcn_mfma_f32_16x16x32_fp8_fp8(ac[mt], bc[nt], acc[mt][nt], 0, 0, 0);
  }

  const int quad = lane>>4, cl = lane&15;
  f32x2 z2 = {0.f,0.f};
  f32x2 rs01[4] = {z2,z2,z2,z2}, rs23[4] = {z2,z2,z2,z2};
  f32x2 cs[4] = {z2,z2,z2,z2};
  #pragma unroll
  for (int mt=0;mt<4;mt++){
    #pragma unroll
    for (int nt=0;nt<4;nt++){
      f32x4 v = acc[mt][nt];
      float e0 = fexp2(v[0]), e1 = fexp2(v[1]);
      float e2 = fexp2(v[2]), e3 = fexp2(v[3]);
      f32x2 p01 = {e0,e1}, p23 = {e2,e3};
      rs01[mt] += p01; rs23[mt] += p23;
      cs[nt] += p01; cs[nt] += p23;
    }
  }
  #pragma unroll
  for (int mt=0;mt<4;mt++){
    union{f32x2 v; double d;} u0, u1;
    u0.v = rs01[mt]; u1.v = rs23[mt];
    #pragma unroll
    for (int m=1;m<16;m<<=1){
      union{double d; f32x2 v;} o0, o1;
      o0.d = __shfl_xor(u0.d, m); o1.d = __shfl_xor(u1.d, m);
      u0.v += o0.v; u1.v += o1.v;
    }
    if (cl==0){
      f32x4 rv = {u0.v.x, u0.v.y, u1.v.x, u1.v.y};
      *(f32x4*)&srow[wave][mt*16 + quad*4] = rv;
    }
  }
  __threadfence_block();
  P[((long)ti*256 + tj)*64 + lane] = srow[wave][lane];
  if (ti != tj){
    #pragma unroll
    for (int nt=0;nt<4;nt++){
      float s = cs[nt].x + cs[nt].y;
      s += __shfl_xor(s,16); s += __shfl_xor(s,32);
      if (quad==0) scol[wave][nt*16 + cl] = s;
    }
    __threadfence_block();
    P[((long)tj*256 + ti)*64 + lane] = scol[wave][lane];
  }
}

// ---- fused final reduce + loss (gram3 P layout: 256x256 grid of 64-slices) ----
__global__ void rloss_k(const float* __restrict__ P, const float* __restrict__ bdot,
                        float* __restrict__ out){
  __shared__ float red[256];
  const float E2 = 7.3890560989306495f;  // exp(2) = diag(refl)
  int t = threadIdx.x;
  int i = blockIdx.x*256 + t;            // 0..8191
  int j = i + NROWS;
  const float* p1 = P + (long)(i>>6)*256*64 + (i&63);
  const float* p2 = P + (long)(j>>6)*256*64 + (j&63);
  float s1 = 0.f, s2 = 0.f;
  #pragma unroll 8
  for (int b=0;b<256;b++){ s1 += p1[b*64]; s2 += p2[b*64]; }
  float lb = 2.f * bdot[i];
  float term = 0.5f * ((logf(s1 - E2) - lb) + (logf(s2 - E2) - lb));
  red[t]=term; __syncthreads();
  for (int st=128; st>0; st>>=1){ if (t<st) red[t]+=red[t+st]; __syncthreads(); }
  if (t==0) atomicAdd(out, red[0] / (float)NROWS);
}

extern "C" void kernel_launch(void* const* d_in, const int* in_sizes, int n_in,
                              void* d_out, int out_size, void* d_ws, size_t ws_size,
                              hipStream_t stream){
  const float* feat1 = (const float*)d_in[0];
  const float* feat2 = (const float*)d_in[1];
  const int*   ei1   = (const int*)d_in[2];
  const float* w1    = (const float*)d_in[3];
  const int*   ei2   = (const int*)d_in[4];
  const float* w2    = (const float*)d_in[5];
  const float* w_l1a = (const float*)d_in[6];
  const float* b_l1a = (const float*)d_in[7];
  const float* w_l1b = (const float*)d_in[8];
  const float* b_l1b = (const float*)d_in[9];
  const float* w_g1  = (const float*)d_in[10];
  const float* b_g1  = (const float*)d_in[11];
  const float* w_g2  = (const float*)d_in[12];
  const float* b_g2  = (const float*)d_in[13];
  const float* w_fc1 = (const float*)d_in[14];
  const float* b_fc1 = (const float*)d_in[15];
  const float* w_fc2 = (const float*)d_in[16];
  const float* b_fc2 = (const float*)d_in[17];

  char* base = (char*)d_ws;
  size_t off = 0;
  auto alloc = [&](size_t bytes)->void*{
    void* r = base + off;
    off = (off + bytes + 255) & ~(size_t)255;
    return r;
  };
  // P (16MB) aliases [0,16MB) = z+xb+ax+s2+part of hh. Liveness: z dead after
  // norm_k; xb after gather32; ax after g34; s2 after gather128; hh after proj1 —
  // all complete before gram3_k. Zf/bdot/CSR live past gram: allocated beyond 20MB.
  float* z    = (float*)alloc((size_t)MROWS*128*4);                 // [0,8M)
  short* xb   = (short*)alloc((size_t)MROWS*32*2);                  // [8M,9M)
  short* ax   = (short*)alloc((size_t)MROWS*32*2);                  // [9M,10M)
  short* s2   = (short*)alloc((size_t)MROWS*128*2);                 // [10M,14M)
  short* hh   = (short*)alloc((size_t)MROWS*128*2);                 // [14M,18M)
  short* t2   = (short*)alloc((size_t)MROWS*64*2);                  // [18M,20M)
  short* wl1a_t = (short*)alloc(512*64*2);
  short* wl1b_t = (short*)alloc(64*32*2);
  short* wg1_t  = (short*)alloc(32*256*2);
  short* wg2_t  = (short*)alloc(256*128*2);
  short* wfc1_t = (short*)alloc(128*64*2);
  short* wfc2_t = (short*)alloc(64*128*2);
  unsigned short* Zf = (unsigned short*)alloc((size_t)MROWS*128);   // fragment-order fp8 (2MB)
  int*   deg1 = (int*)alloc(NROWS*4);                               // zeroed pair
  int*   deg2 = (int*)alloc(NROWS*4);
  int* rs1  = (int*)alloc((NROWS+1)*4);
  int* cur1 = (int*)alloc(NROWS*4);
  int* rs2  = (int*)alloc((NROWS+1)*4);
  int* cur2 = (int*)alloc(NROWS*4);
  int*   ecol1 = (int*)alloc((size_t)NEDGE*4);
  float* ewt1  = (float*)alloc((size_t)NEDGE*4);
  int*   ecol2 = (int*)alloc((size_t)NEDGE*4);
  float* ewt2  = (float*)alloc((size_t)NEDGE*4);
  float* bdot  = (float*)alloc(NROWS*4);
  float* P = (float*)d_ws;   // 16MB alias (see note)

  hipMemsetAsync(deg1, 0, (size_t)2*NROWS*4, stream);
  hipMemsetAsync(d_out, 0, sizeof(float), stream);

  WtArgs wa;
  wa.src[0]=w_l1a; wa.dst[0]=wl1a_t; wa.K[0]=512; wa.N[0]=64;
  wa.src[1]=w_l1b; wa.dst[1]=wl1b_t; wa.K[1]=64;  wa.N[1]=32;
  wa.src[2]=w_g1;  wa.dst[2]=wg1_t;  wa.K[2]=32;  wa.N[2]=256;
  wa.src[3]=w_g2;  wa.dst[3]=wg2_t;  wa.K[3]=256; wa.N[3]=128;
  wa.src[4]=w_fc1; wa.dst[4]=wfc1_t; wa.K[4]=128; wa.N[4]=64;
  wa.src[5]=w_fc2; wa.dst[5]=wfc2_t; wa.K[5]=64;  wa.N[5]=128;
  wa.off[0]=0;
  for (int i=0;i<6;i++) wa.off[i+1] = wa.off[i] + wa.K[i]*wa.N[i];
  wa.nwt = (wa.off[6]+255)/256;
  setup_k<<<wa.nwt + 2*(NEDGE/256),256,0,stream>>>(wa, ei1, ei2, deg1, deg2);
  scan2_k<<<2,256,0,stream>>>(deg1, rs1, cur1, deg2, rs2, cur2);
  fill2_k<<<2*(NEDGE/256),256,0,stream>>>(ei1, w1, cur1, ecol1, ewt1,
                                          ei2, w2, cur2, ecol2, ewt2);

  // encoder (both graphs batched: rows 0..8191 = view1, 8192..16383 = view2)
  mlp12_k<<<MROWS/64,256,0,stream>>>(feat1, feat2, wl1a_t, b_l1a, wl1b_t, b_l1b, xb);
  // layer 1: aggregate FIRST in 32-dim space (adj@(x@W) == (adj@x)@W)
  gather_k<32,false,false><<<MROWS/64,256,0,stream>>>(xb, rs1,ecol1,ewt1, rs2,ecol2,ewt2, nullptr, ax);
  g34_k<<<MROWS/64,256,0,stream>>>(ax, wg1_t, b_g1, wg2_t, s2);
  gather_k<128,false,true><<<MROWS/16,256,0,stream>>>(s2, rs1,ecol1,ewt1, rs2,ecol2,ewt2, b_g2, hh);
  // projection
  gemm_k<64,128,2,true,false><<<MROWS/64,256,0,stream>>>(hh, wfc1_t, b_fc1, t2);
  gemm_k<128,64,0,true,true><<<MROWS/64,256,0,stream>>>(t2, wfc2_t, b_fc2, z);

  norm_k<<<NROWS/4,256,0,stream>>>(z, Zf, bdot);

  gram3_k<<<8224,256,0,stream>>>((const unsigned char*)Zf, P);   // 32896 UT tiles
  rloss_k<<<NROWS/256,256,0,stream>>>(P, bdot, (float*)d_out);
}